// Round 1
// baseline (3310.055 us; speedup 1.0000x reference)
//
#include <hip/hip_runtime.h>

#define N_USERS 100000
#define N_ITEMS 50000
#define N_TOTAL (N_USERS + N_ITEMS)
#define DIM 64
#define NNZ_C 4800000
#define NELEM (N_TOTAL * DIM)        // 9,600,000 floats
#define NELEM4 (NELEM / 4)           // 2,400,000 float4

// init: A = concat(user,item); out = A; B = 0
__global__ __launch_bounds__(256) void init_kernel(
    const float4* __restrict__ user, const float4* __restrict__ item,
    float4* __restrict__ A, float4* __restrict__ B, float4* __restrict__ out) {
    int i = blockIdx.x * 256 + threadIdx.x;
    if (i >= NELEM4) return;
    const int u4 = N_USERS * DIM / 4;
    float4 v = (i < u4) ? user[i] : item[i - u4];
    A[i] = v;
    out[i] = v;
    B[i] = make_float4(0.f, 0.f, 0.f, 0.f);
}

// SpMM scatter: one wave (64 lanes) per nnz; lane = embedding dim.
// y[row[k], lane] += vals[k] * x[col[k], lane]
__global__ __launch_bounds__(256) void spmm_kernel(
    const int* __restrict__ row, const int* __restrict__ col,
    const float* __restrict__ vals,
    const float* __restrict__ x, float* __restrict__ y) {
    int e = blockIdx.x * 256 + threadIdx.x;   // NNZ_C*64 = 307.2M < 2^31
    int k = e >> 6;
    int lane = e & 63;
    if (k >= NNZ_C) return;
    int r = row[k];
    int c = col[k];
    float v = vals[k];
    atomicAdd(&y[(size_t)r * DIM + lane], v * x[(size_t)c * DIM + lane]);
}

// out += src (optionally scaled at the end); zero `zbuf` for next layer.
__global__ __launch_bounds__(256) void acc_kernel(
    float4* __restrict__ out, const float4* __restrict__ src,
    float4* __restrict__ zbuf, float scale) {
    int i = blockIdx.x * 256 + threadIdx.x;
    if (i >= NELEM4) return;
    float4 o = out[i];
    float4 s = src[i];
    o.x = (o.x + s.x) * scale;
    o.y = (o.y + s.y) * scale;
    o.z = (o.z + s.z) * scale;
    o.w = (o.w + s.w) * scale;
    out[i] = o;
    if (zbuf) zbuf[i] = make_float4(0.f, 0.f, 0.f, 0.f);
}

extern "C" void kernel_launch(void* const* d_in, const int* in_sizes, int n_in,
                              void* d_out, int out_size, void* d_ws, size_t ws_size,
                              hipStream_t stream) {
    const float* user_emb = (const float*)d_in[0];
    const float* item_emb = (const float*)d_in[1];
    const int*   adj_row  = (const int*)d_in[2];
    const int*   adj_col  = (const int*)d_in[3];
    const float* adj_vals = (const float*)d_in[4];
    float* out = (float*)d_out;

    float* A = (float*)d_ws;                 // buffer A: N_TOTAL*DIM floats
    float* B = A + NELEM;                    // buffer B: N_TOTAL*DIM floats

    const int eltBlocks  = (NELEM4 + 255) / 256;
    const int spmmBlocks = (NNZ_C * 64) / 256;   // exact: 1,200,000

    // init: A = all_emb, out = all_emb, B = 0
    init_kernel<<<eltBlocks, 256, 0, stream>>>(
        (const float4*)user_emb, (const float4*)item_emb,
        (float4*)A, (float4*)B, (float4*)out);

    // layer 0: A -> B ; out += B ; zero A
    spmm_kernel<<<spmmBlocks, 256, 0, stream>>>(adj_row, adj_col, adj_vals, A, B);
    acc_kernel<<<eltBlocks, 256, 0, stream>>>((float4*)out, (const float4*)B,
                                              (float4*)A, 1.0f);
    // layer 1: B -> A ; out += A ; zero B
    spmm_kernel<<<spmmBlocks, 256, 0, stream>>>(adj_row, adj_col, adj_vals, B, A);
    acc_kernel<<<eltBlocks, 256, 0, stream>>>((float4*)out, (const float4*)A,
                                              (float4*)B, 1.0f);
    // layer 2: A -> B ; out = (out + B) / 4
    spmm_kernel<<<spmmBlocks, 256, 0, stream>>>(adj_row, adj_col, adj_vals, A, B);
    acc_kernel<<<eltBlocks, 256, 0, stream>>>((float4*)out, (const float4*)B,
                                              (float4*)nullptr, 0.25f);
}

// Round 2
// 1748.816 us; speedup vs baseline: 1.8927x; 1.8927x over previous
//
#include <hip/hip_runtime.h>

#define N_USERS 100000
#define N_ITEMS 50000
#define N_TOTAL 150000
#define DIM 64
#define NNZ_C 4800000
#define NELEM (N_TOTAL * DIM)        // 9,600,000 floats
#define NELEM4 (NELEM / 4)           // 2,400,000 float4
#define SCAN_THREADS 1024
#define SCAN_CHUNK ((N_TOTAL + SCAN_THREADS - 1) / SCAN_THREADS)  // 147

// init: A = concat(user,item); out = A; counts = 0
__global__ __launch_bounds__(256) void init_kernel(
    const float4* __restrict__ user, const float4* __restrict__ item,
    float4* __restrict__ A, float4* __restrict__ out, int* __restrict__ counts) {
    int i = blockIdx.x * 256 + threadIdx.x;
    if (i < NELEM4) {
        const int u4 = N_USERS * DIM / 4;
        float4 v = (i < u4) ? user[i] : item[i - u4];
        A[i] = v;
        out[i] = v;
    }
    if (i < N_TOTAL) counts[i] = 0;   // NELEM4 > N_TOTAL, covered
}

__global__ __launch_bounds__(256) void hist_kernel(
    const int* __restrict__ row, int* __restrict__ counts) {
    int k = blockIdx.x * 256 + threadIdx.x;
    if (k < NNZ_C) atomicAdd(&counts[row[k]], 1);
}

// single-block exclusive scan of counts -> rowptr (N+1) and writeptr (N)
__global__ __launch_bounds__(SCAN_THREADS) void scan_kernel(
    const int* __restrict__ counts, int* __restrict__ rowptr,
    int* __restrict__ writeptr) {
    __shared__ int sums[SCAN_THREADS];
    int t = threadIdx.x;
    int lo = t * SCAN_CHUNK;
    int hi = min(lo + SCAN_CHUNK, N_TOTAL);
    int s = 0;
    for (int i = lo; i < hi; i++) s += counts[i];
    sums[t] = s;
    __syncthreads();
    for (int off = 1; off < SCAN_THREADS; off <<= 1) {
        int v = sums[t];
        int w = (t >= off) ? sums[t - off] : 0;
        __syncthreads();
        sums[t] = v + w;
        __syncthreads();
    }
    int run = (t == 0) ? 0 : sums[t - 1];
    for (int i = lo; i < hi; i++) {
        rowptr[i] = run;
        writeptr[i] = run;
        run += counts[i];
    }
    if (t == SCAN_THREADS - 1) rowptr[N_TOTAL] = sums[SCAN_THREADS - 1];
}

__global__ __launch_bounds__(256) void scatter_kernel(
    const int* __restrict__ row, const int* __restrict__ col,
    const float* __restrict__ vals, int* __restrict__ writeptr,
    int* __restrict__ csr_col, float* __restrict__ csr_val) {
    int k = blockIdx.x * 256 + threadIdx.x;
    if (k >= NNZ_C) return;
    int r = row[k];
    int p = atomicAdd(&writeptr[r], 1);
    csr_col[p] = col[k];
    csr_val[p] = vals[k];
}

// one wave per row: y[r,:] = sum_j val[j] * x[col[j],:]
// fused: out[r,:] = (out[r,:] + y[r,:]) * scale
__global__ __launch_bounds__(256) void spmm_csr_kernel(
    const int* __restrict__ rowptr, const int* __restrict__ csr_col,
    const float* __restrict__ csr_val, const float* __restrict__ x,
    float* __restrict__ y, float* __restrict__ out, float scale) {
    int gid = blockIdx.x * 256 + threadIdx.x;
    int r = gid >> 6;
    int lane = gid & 63;
    if (r >= N_TOTAL) return;
    int start = rowptr[r], end = rowptr[r + 1];
    float acc = 0.f;
    for (int base = start; base < end; base += 64) {
        int j = base + lane;
        int c = 0;
        float v = 0.f;
        if (j < end) { c = csr_col[j]; v = csr_val[j]; }
        int cnt = min(64, end - base);
        for (int t = 0; t < cnt; t++) {
            int cc = __shfl(c, t);
            float vv = __shfl(v, t);
            acc += vv * x[cc * DIM + lane];
        }
    }
    int o = r * DIM + lane;
    y[o] = acc;
    out[o] = (out[o] + acc) * scale;
}

extern "C" void kernel_launch(void* const* d_in, const int* in_sizes, int n_in,
                              void* d_out, int out_size, void* d_ws, size_t ws_size,
                              hipStream_t stream) {
    const float* user_emb = (const float*)d_in[0];
    const float* item_emb = (const float*)d_in[1];
    const int*   adj_row  = (const int*)d_in[2];
    const int*   adj_col  = (const int*)d_in[3];
    const float* adj_vals = (const float*)d_in[4];
    float* out = (float*)d_out;

    float* A        = (float*)d_ws;
    float* B        = A + NELEM;
    int*   csr_col  = (int*)(B + NELEM);
    float* csr_val  = (float*)(csr_col + NNZ_C);
    int*   rowptr   = (int*)(csr_val + NNZ_C);
    int*   writeptr = rowptr + N_TOTAL + 1;
    int*   counts   = writeptr + N_TOTAL;   // scratch histogram

    const int eltBlocks  = (NELEM4 + 255) / 256;
    const int nnzBlocks  = (NNZ_C + 255) / 256;
    const int spmmBlocks = (N_TOTAL * 64) / 256;  // 37,500

    init_kernel<<<eltBlocks, 256, 0, stream>>>(
        (const float4*)user_emb, (const float4*)item_emb,
        (float4*)A, (float4*)out, counts);
    hist_kernel<<<nnzBlocks, 256, 0, stream>>>(adj_row, counts);
    scan_kernel<<<1, SCAN_THREADS, 0, stream>>>(counts, rowptr, writeptr);
    scatter_kernel<<<nnzBlocks, 256, 0, stream>>>(adj_row, adj_col, adj_vals,
                                                  writeptr, csr_col, csr_val);

    // layer 0: A -> B ; out += B
    spmm_csr_kernel<<<spmmBlocks, 256, 0, stream>>>(rowptr, csr_col, csr_val,
                                                    A, B, out, 1.0f);
    // layer 1: B -> A ; out += A
    spmm_csr_kernel<<<spmmBlocks, 256, 0, stream>>>(rowptr, csr_col, csr_val,
                                                    B, A, out, 1.0f);
    // layer 2: A -> B ; out = (out + B) / 4
    spmm_csr_kernel<<<spmmBlocks, 256, 0, stream>>>(rowptr, csr_col, csr_val,
                                                    A, B, out, 0.25f);
}

// Round 3
// 1228.629 us; speedup vs baseline: 2.6941x; 1.4234x over previous
//
#include <hip/hip_runtime.h>

#define N_USERS 100000
#define N_ITEMS 50000
#define N_TOTAL 150000
#define DIM 64
#define NNZ_C 4800000
#define NELEM (N_TOTAL * DIM)        // 9,600,000 floats
#define NELEM4 (NELEM / 4)           // 2,400,000 float4
#define SCAN_BLK 1024
#define SCAN_NB ((N_TOTAL + SCAN_BLK - 1) / SCAN_BLK)   // 147

// init: A = concat(user,item); out = A; counts = 0
__global__ __launch_bounds__(256) void init_kernel(
    const float4* __restrict__ user, const float4* __restrict__ item,
    float4* __restrict__ A, float4* __restrict__ out, int* __restrict__ counts) {
    int i = blockIdx.x * 256 + threadIdx.x;
    if (i < NELEM4) {
        const int u4 = N_USERS * DIM / 4;
        float4 v = (i < u4) ? user[i] : item[i - u4];
        A[i] = v;
        out[i] = v;
    }
    if (i < N_TOTAL) counts[i] = 0;
}

__global__ __launch_bounds__(256) void hist_kernel(
    const int* __restrict__ row, int* __restrict__ counts) {
    int k = blockIdx.x * 256 + threadIdx.x;
    if (k < NNZ_C) atomicAdd(&counts[row[k]], 1);
}

// pass A: per-block exclusive scan of 1024 counts + block total
__global__ __launch_bounds__(SCAN_BLK) void scanA_kernel(
    const int* __restrict__ counts, int* __restrict__ excl,
    int* __restrict__ blocksums) {
    __shared__ int s[SCAN_BLK];
    int t = threadIdx.x;
    int i = blockIdx.x * SCAN_BLK + t;
    int v = (i < N_TOTAL) ? counts[i] : 0;
    s[t] = v;
    __syncthreads();
    for (int off = 1; off < SCAN_BLK; off <<= 1) {
        int w = (t >= off) ? s[t - off] : 0;
        __syncthreads();
        s[t] += w;
        __syncthreads();
    }
    if (i < N_TOTAL) excl[i] = s[t] - v;
    if (t == SCAN_BLK - 1) blocksums[blockIdx.x] = s[t];
}

// pass B: single small block scans the 147 block sums (exclusive, in place)
__global__ __launch_bounds__(256) void scanB_kernel(int* __restrict__ blocksums) {
    __shared__ int s[256];
    int t = threadIdx.x;
    int v = (t < SCAN_NB) ? blocksums[t] : 0;
    s[t] = v;
    __syncthreads();
    for (int off = 1; off < 256; off <<= 1) {
        int w = (t >= off) ? s[t - off] : 0;
        __syncthreads();
        s[t] += w;
        __syncthreads();
    }
    if (t < SCAN_NB) blocksums[t] = s[t] - v;
}

// pass C: rowptr[i] = excl[i] + blockoff[i>>10]; writeptr = rowptr
__global__ __launch_bounds__(256) void scanC_kernel(
    const int* __restrict__ excl, const int* __restrict__ blocksums,
    int* __restrict__ rowptr, int* __restrict__ writeptr) {
    int i = blockIdx.x * 256 + threadIdx.x;
    if (i < N_TOTAL) {
        int v = excl[i] + blocksums[i >> 10];
        rowptr[i] = v;
        writeptr[i] = v;
    }
    if (i == 0) rowptr[N_TOTAL] = NNZ_C;
}

// scatter into packed (col, val) pairs — one 8B store per nnz
__global__ __launch_bounds__(256) void scatter_kernel(
    const int* __restrict__ row, const int* __restrict__ col,
    const float* __restrict__ vals, int* __restrict__ writeptr,
    int2* __restrict__ csr) {
    int k = blockIdx.x * 256 + threadIdx.x;
    if (k >= NNZ_C) return;
    int r = row[k];
    int p = atomicAdd(&writeptr[r], 1);
    csr[p] = make_int2(col[k], __float_as_int(vals[k]));
}

// 4 rows per wave, 16 lanes per row, float4 gathers.
// y[r,:] = sum_j val[j] * x[col[j],:];  out[r,:] = (out[r,:] + y[r,:]) * scale
__global__ __launch_bounds__(256) void spmm_csr_kernel(
    const int* __restrict__ rowptr, const int2* __restrict__ csr,
    const float4* __restrict__ x, float4* __restrict__ y,
    float4* __restrict__ out, float scale) {
    int gid = blockIdx.x * 256 + threadIdx.x;
    int lane = threadIdx.x & 63;
    int group = lane >> 4;          // 0..3: which row within the wave
    int chunk = lane & 15;          // float4 chunk of the row
    int r = (gid >> 6) * 4 + group;
    if (r >= N_TOTAL) return;
    int start = rowptr[r], end = rowptr[r + 1];
    float4 acc = make_float4(0.f, 0.f, 0.f, 0.f);
    for (int j0 = start; j0 < end; j0 += 16) {
        int j = j0 + chunk;
        int2 pair = make_int2(0, 0);
        if (j < end) pair = csr[j];
        int cnt = min(16, end - j0);
        #pragma unroll 4
        for (int t = 0; t < cnt; t++) {
            int src = group * 16 + t;
            int cc = __shfl(pair.x, src);
            float vv = __int_as_float(__shfl(pair.y, src));
            float4 xv = x[cc * 16 + chunk];
            acc.x += vv * xv.x;
            acc.y += vv * xv.y;
            acc.z += vv * xv.z;
            acc.w += vv * xv.w;
        }
    }
    int o = r * 16 + chunk;
    y[o] = acc;
    float4 oo = out[o];
    oo.x = (oo.x + acc.x) * scale;
    oo.y = (oo.y + acc.y) * scale;
    oo.z = (oo.z + acc.z) * scale;
    oo.w = (oo.w + acc.w) * scale;
    out[o] = oo;
}

extern "C" void kernel_launch(void* const* d_in, const int* in_sizes, int n_in,
                              void* d_out, int out_size, void* d_ws, size_t ws_size,
                              hipStream_t stream) {
    const float* user_emb = (const float*)d_in[0];
    const float* item_emb = (const float*)d_in[1];
    const int*   adj_row  = (const int*)d_in[2];
    const int*   adj_col  = (const int*)d_in[3];
    const float* adj_vals = (const float*)d_in[4];
    float* out = (float*)d_out;

    float* A         = (float*)d_ws;            // 9.6M floats
    float* B         = A + NELEM;               // 9.6M floats
    int2*  csr       = (int2*)(B + NELEM);      // 4.8M int2
    int*   rowptr    = (int*)(csr + NNZ_C);     // N+1
    int*   writeptr  = rowptr + N_TOTAL + 1;    // N
    int*   counts    = writeptr + N_TOTAL;      // N
    int*   excl      = counts + N_TOTAL;        // N
    int*   blocksums = excl + N_TOTAL;          // 147

    const int eltBlocks  = (NELEM4 + 255) / 256;
    const int nnzBlocks  = (NNZ_C + 255) / 256;
    const int rowBlocks  = (N_TOTAL + 255) / 256;
    const int spmmBlocks = N_TOTAL / 16;        // 9375 (exact)

    init_kernel<<<eltBlocks, 256, 0, stream>>>(
        (const float4*)user_emb, (const float4*)item_emb,
        (float4*)A, (float4*)out, counts);
    hist_kernel<<<nnzBlocks, 256, 0, stream>>>(adj_row, counts);
    scanA_kernel<<<SCAN_NB, SCAN_BLK, 0, stream>>>(counts, excl, blocksums);
    scanB_kernel<<<1, 256, 0, stream>>>(blocksums);
    scanC_kernel<<<rowBlocks, 256, 0, stream>>>(excl, blocksums, rowptr, writeptr);
    scatter_kernel<<<nnzBlocks, 256, 0, stream>>>(adj_row, adj_col, adj_vals,
                                                  writeptr, csr);

    spmm_csr_kernel<<<spmmBlocks, 256, 0, stream>>>(rowptr, csr,
        (const float4*)A, (float4*)B, (float4*)out, 1.0f);
    spmm_csr_kernel<<<spmmBlocks, 256, 0, stream>>>(rowptr, csr,
        (const float4*)B, (float4*)A, (float4*)out, 1.0f);
    spmm_csr_kernel<<<spmmBlocks, 256, 0, stream>>>(rowptr, csr,
        (const float4*)A, (float4*)B, (float4*)out, 0.25f);
}

// Round 4
// 1114.689 us; speedup vs baseline: 2.9695x; 1.1022x over previous
//
#include <hip/hip_runtime.h>

#define N_USERS 100000
#define N_ITEMS 50000
#define N_TOTAL 150000
#define DIM 64
#define NNZ_C 4800000
#define NELEM (N_TOTAL * DIM)        // 9,600,000 floats
#define NELEM4 (NELEM / 4)           // 2,400,000 float4
#define SCAN_BLK 1024
#define SCAN_NB ((N_TOTAL + SCAN_BLK - 1) / SCAN_BLK)   // 147
#define R_SPLIT 4
#define R_CHUNK (N_TOTAL / R_SPLIT)  // 37,500 rows per scatter pass

// init: A = concat(user,item); out = A; counts = 0
__global__ __launch_bounds__(256) void init_kernel(
    const float4* __restrict__ user, const float4* __restrict__ item,
    float4* __restrict__ A, float4* __restrict__ out, int* __restrict__ counts) {
    int i = blockIdx.x * 256 + threadIdx.x;
    if (i < NELEM4) {
        const int u4 = N_USERS * DIM / 4;
        float4 v = (i < u4) ? user[i] : item[i - u4];
        A[i] = v;
        out[i] = v;
    }
    if (i < N_TOTAL) counts[i] = 0;
}

__global__ __launch_bounds__(256) void hist_kernel(
    const int* __restrict__ row, int* __restrict__ counts) {
    int k = blockIdx.x * 256 + threadIdx.x;
    if (k < NNZ_C) atomicAdd(&counts[row[k]], 1);
}

// pass A: per-block exclusive scan of 1024 counts + block total
__global__ __launch_bounds__(SCAN_BLK) void scanA_kernel(
    const int* __restrict__ counts, int* __restrict__ excl,
    int* __restrict__ blocksums) {
    __shared__ int s[SCAN_BLK];
    int t = threadIdx.x;
    int i = blockIdx.x * SCAN_BLK + t;
    int v = (i < N_TOTAL) ? counts[i] : 0;
    s[t] = v;
    __syncthreads();
    for (int off = 1; off < SCAN_BLK; off <<= 1) {
        int w = (t >= off) ? s[t - off] : 0;
        __syncthreads();
        s[t] += w;
        __syncthreads();
    }
    if (i < N_TOTAL) excl[i] = s[t] - v;
    if (t == SCAN_BLK - 1) blocksums[blockIdx.x] = s[t];
}

// pass B: single small block scans the 147 block sums (exclusive, in place)
__global__ __launch_bounds__(256) void scanB_kernel(int* __restrict__ blocksums) {
    __shared__ int s[256];
    int t = threadIdx.x;
    int v = (t < SCAN_NB) ? blocksums[t] : 0;
    s[t] = v;
    __syncthreads();
    for (int off = 1; off < 256; off <<= 1) {
        int w = (t >= off) ? s[t - off] : 0;
        __syncthreads();
        s[t] += w;
        __syncthreads();
    }
    if (t < SCAN_NB) blocksums[t] = s[t] - v;
}

// pass C: rowptr[i] = excl[i] + blockoff[i>>10]; writeptr = rowptr
__global__ __launch_bounds__(256) void scanC_kernel(
    const int* __restrict__ excl, const int* __restrict__ blocksums,
    int* __restrict__ rowptr, int* __restrict__ writeptr) {
    int i = blockIdx.x * 256 + threadIdx.x;
    if (i < N_TOTAL) {
        int v = excl[i] + blocksums[i >> 10];
        rowptr[i] = v;
        writeptr[i] = v;
    }
    if (i == 0) rowptr[N_TOTAL] = NNZ_C;
}

// range-filtered scatter: only rows in [rlo, rhi) are written this pass,
// keeping the active CSR write footprint (~9.6 MB) L2-resident so each
// 64B frontier line absorbs all 8 of its 8B entries before writeback.
__global__ __launch_bounds__(256) void scatter_kernel(
    const int* __restrict__ row, const int* __restrict__ col,
    const float* __restrict__ vals, int* __restrict__ writeptr,
    int2* __restrict__ csr, int rlo, int rhi) {
    int k = blockIdx.x * 256 + threadIdx.x;
    if (k >= NNZ_C) return;
    int r = row[k];
    if (r < rlo || r >= rhi) return;
    int p = atomicAdd(&writeptr[r], 1);
    csr[p] = make_int2(col[k], __float_as_int(vals[k]));
}

// 4 rows per wave, 16 lanes per row, float4 gathers.
// y[r,:] = sum_j val[j] * x[col[j],:];  out[r,:] = (out[r,:] + y[r,:]) * scale
__global__ __launch_bounds__(256) void spmm_csr_kernel(
    const int* __restrict__ rowptr, const int2* __restrict__ csr,
    const float4* __restrict__ x, float4* __restrict__ y,
    float4* __restrict__ out, float scale) {
    int gid = blockIdx.x * 256 + threadIdx.x;
    int lane = threadIdx.x & 63;
    int group = lane >> 4;          // 0..3: which row within the wave
    int chunk = lane & 15;          // float4 chunk of the row
    int r = (gid >> 6) * 4 + group;
    if (r >= N_TOTAL) return;
    int start = rowptr[r], end = rowptr[r + 1];
    float4 acc = make_float4(0.f, 0.f, 0.f, 0.f);
    for (int j0 = start; j0 < end; j0 += 16) {
        int j = j0 + chunk;
        int2 pair = make_int2(0, 0);
        if (j < end) pair = csr[j];
        int cnt = min(16, end - j0);
        #pragma unroll 4
        for (int t = 0; t < cnt; t++) {
            int src = group * 16 + t;
            int cc = __shfl(pair.x, src);
            float vv = __int_as_float(__shfl(pair.y, src));
            float4 xv = x[cc * 16 + chunk];
            acc.x += vv * xv.x;
            acc.y += vv * xv.y;
            acc.z += vv * xv.z;
            acc.w += vv * xv.w;
        }
    }
    int o = r * 16 + chunk;
    y[o] = acc;
    float4 oo = out[o];
    oo.x = (oo.x + acc.x) * scale;
    oo.y = (oo.y + acc.y) * scale;
    oo.z = (oo.z + acc.z) * scale;
    oo.w = (oo.w + acc.w) * scale;
    out[o] = oo;
}

extern "C" void kernel_launch(void* const* d_in, const int* in_sizes, int n_in,
                              void* d_out, int out_size, void* d_ws, size_t ws_size,
                              hipStream_t stream) {
    const float* user_emb = (const float*)d_in[0];
    const float* item_emb = (const float*)d_in[1];
    const int*   adj_row  = (const int*)d_in[2];
    const int*   adj_col  = (const int*)d_in[3];
    const float* adj_vals = (const float*)d_in[4];
    float* out = (float*)d_out;

    float* A         = (float*)d_ws;            // 9.6M floats
    float* B         = A + NELEM;               // 9.6M floats
    int2*  csr       = (int2*)(B + NELEM);      // 4.8M int2
    int*   rowptr    = (int*)(csr + NNZ_C);     // N+1
    int*   writeptr  = rowptr + N_TOTAL + 1;    // N
    int*   counts    = writeptr + N_TOTAL;      // N
    int*   excl      = counts + N_TOTAL;        // N
    int*   blocksums = excl + N_TOTAL;          // 147

    const int eltBlocks  = (NELEM4 + 255) / 256;
    const int nnzBlocks  = (NNZ_C + 255) / 256;
    const int rowBlocks  = (N_TOTAL + 255) / 256;
    const int spmmBlocks = N_TOTAL / 16;        // 9375 (exact)

    init_kernel<<<eltBlocks, 256, 0, stream>>>(
        (const float4*)user_emb, (const float4*)item_emb,
        (float4*)A, (float4*)out, counts);
    hist_kernel<<<nnzBlocks, 256, 0, stream>>>(adj_row, counts);
    scanA_kernel<<<SCAN_NB, SCAN_BLK, 0, stream>>>(counts, excl, blocksums);
    scanB_kernel<<<1, 256, 0, stream>>>(blocksums);
    scanC_kernel<<<rowBlocks, 256, 0, stream>>>(excl, blocksums, rowptr, writeptr);
    for (int p = 0; p < R_SPLIT; p++) {
        scatter_kernel<<<nnzBlocks, 256, 0, stream>>>(adj_row, adj_col, adj_vals,
                                                      writeptr, csr,
                                                      p * R_CHUNK, (p + 1) * R_CHUNK);
    }

    spmm_csr_kernel<<<spmmBlocks, 256, 0, stream>>>(rowptr, csr,
        (const float4*)A, (float4*)B, (float4*)out, 1.0f);
    spmm_csr_kernel<<<spmmBlocks, 256, 0, stream>>>(rowptr, csr,
        (const float4*)B, (float4*)A, (float4*)out, 1.0f);
    spmm_csr_kernel<<<spmmBlocks, 256, 0, stream>>>(rowptr, csr,
        (const float4*)A, (float4*)B, (float4*)out, 0.25f);
}

// Round 5
// 885.280 us; speedup vs baseline: 3.7390x; 1.2591x over previous
//
#include <hip/hip_runtime.h>

#define N_USERS 100000
#define N_ITEMS 50000
#define N_TOTAL 150000
#define DIM 64
#define NNZ_C 4800000
#define NELEM (N_TOTAL * DIM)        // 9,600,000 elements
#define NELEM4 (NELEM / 4)           // 2,400,000 x4-vectors
#define SCAN_BLK 1024
#define SCAN_NB ((N_TOTAL + SCAN_BLK - 1) / SCAN_BLK)   // 147
#define R_SPLIT 4
#define R_CHUNK (N_TOTAL / R_SPLIT)  // 37,500 rows per scatter pass
#define NXCD 8

typedef unsigned short ush;

__device__ __forceinline__ unsigned xcc_id() {
    unsigned x;
    asm volatile("s_getreg_b32 %0, hwreg(HW_REG_XCC_ID)" : "=s"(x));
    return x & (NXCD - 1);
}

__device__ __forceinline__ float bf2f(ush u) {
    return __uint_as_float(((unsigned)u) << 16);
}
__device__ __forceinline__ ush f2bf(float f) {   // round-to-nearest-even
    unsigned u = __float_as_uint(f);
    return (ush)((u + 0x7fffu + ((u >> 16) & 1u)) >> 16);
}

// init: A(bf16) = concat(user,item); out(fp32) = same; counts8 = 0
__global__ __launch_bounds__(256) void init_kernel(
    const float4* __restrict__ user, const float4* __restrict__ item,
    ushort4* __restrict__ A16, float4* __restrict__ out,
    int* __restrict__ counts8) {
    int i = blockIdx.x * 256 + threadIdx.x;
    if (i < NELEM4) {
        const int u4 = N_USERS * DIM / 4;
        float4 v = (i < u4) ? user[i] : item[i - u4];
        ushort4 b;
        b.x = f2bf(v.x); b.y = f2bf(v.y); b.z = f2bf(v.z); b.w = f2bf(v.w);
        A16[i] = b;
        out[i] = v;
    }
    if (i < NXCD * N_TOTAL) counts8[i] = 0;   // 1.2M < NELEM4, covered
}

// XCD-local histogram: workgroup-scope atomic executes in the local TCC
// (stays in the per-XCD L2 — no memory-side write-through). Each physical
// XCD owns its counts8 slice, so TCC-local RMW is correct; kernel-end
// agent release writes the slices back.
__global__ __launch_bounds__(256) void hist_kernel(
    const int* __restrict__ row, int* __restrict__ counts8) {
    int k = blockIdx.x * 256 + threadIdx.x;
    if (k >= NNZ_C) return;
    unsigned x = xcc_id();
    __hip_atomic_fetch_add(&counts8[x * N_TOTAL + row[k]], 1,
                           __ATOMIC_RELAXED, __HIP_MEMORY_SCOPE_WORKGROUP);
}

// pass A: sum 8 XCD slices, per-block exclusive scan + block total
__global__ __launch_bounds__(SCAN_BLK) void scanA_kernel(
    const int* __restrict__ counts8, int* __restrict__ excl,
    int* __restrict__ blocksums) {
    __shared__ int s[SCAN_BLK];
    int t = threadIdx.x;
    int i = blockIdx.x * SCAN_BLK + t;
    int v = 0;
    if (i < N_TOTAL)
        for (int x = 0; x < NXCD; x++) v += counts8[x * N_TOTAL + i];
    s[t] = v;
    __syncthreads();
    for (int off = 1; off < SCAN_BLK; off <<= 1) {
        int w = (t >= off) ? s[t - off] : 0;
        __syncthreads();
        s[t] += w;
        __syncthreads();
    }
    if (i < N_TOTAL) excl[i] = s[t] - v;
    if (t == SCAN_BLK - 1) blocksums[blockIdx.x] = s[t];
}

// pass B: single block scans the 147 block sums (exclusive, in place)
__global__ __launch_bounds__(256) void scanB_kernel(int* __restrict__ blocksums) {
    __shared__ int s[256];
    int t = threadIdx.x;
    int v = (t < SCAN_NB) ? blocksums[t] : 0;
    s[t] = v;
    __syncthreads();
    for (int off = 1; off < 256; off <<= 1) {
        int w = (t >= off) ? s[t - off] : 0;
        __syncthreads();
        s[t] += w;
        __syncthreads();
    }
    if (t < SCAN_NB) blocksums[t] = s[t] - v;
}

// pass C: rowptr[i] = excl[i] + blockoff[i>>10]; writeptr = rowptr
__global__ __launch_bounds__(256) void scanC_kernel(
    const int* __restrict__ excl, const int* __restrict__ blocksums,
    int* __restrict__ rowptr, int* __restrict__ writeptr) {
    int i = blockIdx.x * 256 + threadIdx.x;
    if (i < N_TOTAL) {
        int v = excl[i] + blocksums[i >> 10];
        rowptr[i] = v;
        writeptr[i] = v;
    }
    if (i == 0) rowptr[N_TOTAL] = NNZ_C;
}

// range-filtered scatter (active CSR write window ~9.6MB stays L2-resident)
__global__ __launch_bounds__(256) void scatter_kernel(
    const int* __restrict__ row, const int* __restrict__ col,
    const float* __restrict__ vals, int* __restrict__ writeptr,
    int2* __restrict__ csr, int rlo, int rhi) {
    int k = blockIdx.x * 256 + threadIdx.x;
    if (k >= NNZ_C) return;
    int r = row[k];
    if (r < rlo || r >= rhi) return;
    int p = atomicAdd(&writeptr[r], 1);
    csr[p] = make_int2(col[k], __float_as_int(vals[k]));
}

// 4 rows/wave, 16 lanes/row, bf16 x gathers (8B/lane = 128B/row).
// y(bf16)[r,:] = sum_j val[j]*x[col[j],:];  out(fp32)[r,:] = (out + acc)*scale
__global__ __launch_bounds__(256) void spmm_csr_kernel(
    const int* __restrict__ rowptr, const int2* __restrict__ csr,
    const ushort4* __restrict__ x4, ushort4* __restrict__ y4,
    float4* __restrict__ out, float scale) {
    int gid = blockIdx.x * 256 + threadIdx.x;
    int lane = threadIdx.x & 63;
    int group = lane >> 4;          // 0..3: row within wave
    int chunk = lane & 15;          // 4-dim chunk of the row
    int r = (gid >> 6) * 4 + group;
    if (r >= N_TOTAL) return;
    int start = rowptr[r], end = rowptr[r + 1];
    float4 acc = make_float4(0.f, 0.f, 0.f, 0.f);
    for (int j0 = start; j0 < end; j0 += 16) {
        int j = j0 + chunk;
        int2 pair = make_int2(0, 0);
        if (j < end) pair = csr[j];
        int cnt = min(16, end - j0);
        #pragma unroll 4
        for (int t = 0; t < cnt; t++) {
            int src = group * 16 + t;
            int cc = __shfl(pair.x, src);
            float vv = __int_as_float(__shfl(pair.y, src));
            ushort4 xv = x4[cc * 16 + chunk];
            acc.x += vv * bf2f(xv.x);
            acc.y += vv * bf2f(xv.y);
            acc.z += vv * bf2f(xv.z);
            acc.w += vv * bf2f(xv.w);
        }
    }
    int o = r * 16 + chunk;
    ushort4 yb;
    yb.x = f2bf(acc.x); yb.y = f2bf(acc.y);
    yb.z = f2bf(acc.z); yb.w = f2bf(acc.w);
    y4[o] = yb;
    float4 oo = out[o];
    oo.x = (oo.x + acc.x) * scale;
    oo.y = (oo.y + acc.y) * scale;
    oo.z = (oo.z + acc.z) * scale;
    oo.w = (oo.w + acc.w) * scale;
    out[o] = oo;
}

extern "C" void kernel_launch(void* const* d_in, const int* in_sizes, int n_in,
                              void* d_out, int out_size, void* d_ws, size_t ws_size,
                              hipStream_t stream) {
    const float* user_emb = (const float*)d_in[0];
    const float* item_emb = (const float*)d_in[1];
    const int*   adj_row  = (const int*)d_in[2];
    const int*   adj_col  = (const int*)d_in[3];
    const float* adj_vals = (const float*)d_in[4];
    float* out = (float*)d_out;

    ush*   A         = (ush*)d_ws;              // NELEM bf16 (19.2 MB)
    ush*   B         = A + NELEM;               // NELEM bf16 (19.2 MB)
    int2*  csr       = (int2*)(B + NELEM);      // 4.8M int2 (38.4 MB)
    int*   rowptr    = (int*)(csr + NNZ_C);     // N+1
    int*   writeptr  = rowptr + N_TOTAL + 1;    // N
    int*   counts8   = writeptr + N_TOTAL;      // 8*N
    int*   excl      = counts8 + NXCD * N_TOTAL; // N
    int*   blocksums = excl + N_TOTAL;          // 147

    const int eltBlocks  = (NELEM4 + 255) / 256;
    const int nnzBlocks  = (NNZ_C + 255) / 256;
    const int rowBlocks  = (N_TOTAL + 255) / 256;
    const int spmmBlocks = N_TOTAL / 16;        // 9375 (exact)

    init_kernel<<<eltBlocks, 256, 0, stream>>>(
        (const float4*)user_emb, (const float4*)item_emb,
        (ushort4*)A, (float4*)out, counts8);
    hist_kernel<<<nnzBlocks, 256, 0, stream>>>(adj_row, counts8);
    scanA_kernel<<<SCAN_NB, SCAN_BLK, 0, stream>>>(counts8, excl, blocksums);
    scanB_kernel<<<1, 256, 0, stream>>>(blocksums);
    scanC_kernel<<<rowBlocks, 256, 0, stream>>>(excl, blocksums, rowptr, writeptr);
    for (int p = 0; p < R_SPLIT; p++) {
        scatter_kernel<<<nnzBlocks, 256, 0, stream>>>(adj_row, adj_col, adj_vals,
                                                      writeptr, csr,
                                                      p * R_CHUNK, (p + 1) * R_CHUNK);
    }

    spmm_csr_kernel<<<spmmBlocks, 256, 0, stream>>>(rowptr, csr,
        (const ushort4*)A, (ushort4*)B, (float4*)out, 1.0f);
    spmm_csr_kernel<<<spmmBlocks, 256, 0, stream>>>(rowptr, csr,
        (const ushort4*)B, (ushort4*)A, (float4*)out, 1.0f);
    spmm_csr_kernel<<<spmmBlocks, 256, 0, stream>>>(rowptr, csr,
        (const ushort4*)A, (ushort4*)B, (float4*)out, 0.25f);
}

// Round 6
// 638.837 us; speedup vs baseline: 5.1814x; 1.3858x over previous
//
#include <hip/hip_runtime.h>

#define N_USERS 100000
#define N_ITEMS 50000
#define N_TOTAL 150000
#define DIM 64
#define NNZ_C 4800000
#define NELEM (N_TOTAL * DIM)        // 9,600,000 elements
#define NELEM4 (NELEM / 4)           // 2,400,000 x4-vectors

#define RPB 74                       // rows per bucket
#define NB 2048                      // buckets (2048*74 >= 150000)
#define NBLK 512                     // scatter blocks
#define CHUNK (NNZ_C / NBLK)         // 9375 nnz per scatter block (exact)
#define CAP 4096                     // max entries/bucket staged (mean 2344)

typedef unsigned short ush;

__device__ __forceinline__ float bf2f(ush u) {
    return __uint_as_float(((unsigned)u) << 16);
}
__device__ __forceinline__ ush f2bf(float f) {   // round-to-nearest-even
    unsigned u = __float_as_uint(f);
    return (ush)((u + 0x7fffu + ((u >> 16) & 1u)) >> 16);
}

// init: A(bf16) = concat(user,item); out(fp32) = same
__global__ __launch_bounds__(256) void init_kernel(
    const float4* __restrict__ user, const float4* __restrict__ item,
    ushort4* __restrict__ A16, float4* __restrict__ out) {
    int i = blockIdx.x * 256 + threadIdx.x;
    if (i >= NELEM4) return;
    const int u4 = N_USERS * DIM / 4;
    float4 v = (i < u4) ? user[i] : item[i - u4];
    ushort4 b;
    b.x = f2bf(v.x); b.y = f2bf(v.y); b.z = f2bf(v.z); b.w = f2bf(v.w);
    A16[i] = b;
    out[i] = v;
}

// P1: per-block bucket histogram in LDS (no global atomics),
// coalesced flush to histmat[block][bucket].
__global__ __launch_bounds__(256) void p1_hist(
    const int* __restrict__ row, int* __restrict__ histmat) {
    __shared__ int h[NB];
    int t = threadIdx.x, b = blockIdx.x;
    for (int j = t; j < NB; j += 256) h[j] = 0;
    __syncthreads();
    int kbeg = b * CHUNK, kend = kbeg + CHUNK;
    for (int k = kbeg + t; k < kend; k += 256) {
        unsigned r = (unsigned)row[k];
        atomicAdd(&h[r / RPB], 1);
    }
    __syncthreads();
    for (int j = t; j < NB; j += 256) histmat[b * NB + j] = h[j];
}

// P2a: column-wise running sum over blocks: basemat[b][j] = sum_{b'<b} hist,
// T[j] = bucket total. 2048 threads, coalesced rows.
__global__ __launch_bounds__(256) void p2a_colscan(
    const int* __restrict__ histmat, int* __restrict__ basemat,
    int* __restrict__ T) {
    int j = blockIdx.x * 256 + threadIdx.x;   // 0..NB-1
    int run = 0;
    for (int b = 0; b < NBLK; b++) {
        basemat[b * NB + j] = run;
        run += histmat[b * NB + j];
    }
    T[j] = run;
}

// P2b: single block exclusive scan of T[2048] -> bucketbase[0..2048]
__global__ __launch_bounds__(1024) void p2b_scan(
    const int* __restrict__ T, int* __restrict__ bucketbase,
    int* __restrict__ rowptr) {
    __shared__ int s[1024];
    int t = threadIdx.x;
    int v0 = T[2 * t], v1 = T[2 * t + 1];
    int pair = v0 + v1;
    s[t] = pair;
    __syncthreads();
    for (int off = 1; off < 1024; off <<= 1) {
        int w = (t >= off) ? s[t - off] : 0;
        __syncthreads();
        s[t] += w;
        __syncthreads();
    }
    int excl = s[t] - pair;
    bucketbase[2 * t] = excl;
    bucketbase[2 * t + 1] = excl + v0;
    if (t == 1023) { bucketbase[NB] = s[t]; rowptr[N_TOTAL] = NNZ_C; }
}

// P3: deterministic scatter into bucket-grouped entries. Slot comes from a
// per-block LDS running pointer seeded with bucketbase+basemat — zero global
// atomics. Entry packs (row_local<<18 | col, val_bits).
__global__ __launch_bounds__(256) void p3_scatter(
    const int* __restrict__ row, const int* __restrict__ col,
    const float* __restrict__ vals, const int* __restrict__ basemat,
    const int* __restrict__ bucketbase, uint2* __restrict__ entries) {
    __shared__ int lbase[NB];
    int t = threadIdx.x, b = blockIdx.x;
    for (int j = t; j < NB; j += 256)
        lbase[j] = bucketbase[j] + basemat[b * NB + j];
    __syncthreads();
    int kbeg = b * CHUNK, kend = kbeg + CHUNK;
    for (int k = kbeg + t; k < kend; k += 256) {
        unsigned r = (unsigned)row[k];
        unsigned j = r / RPB;
        unsigned rl = r - j * RPB;
        int slot = atomicAdd(&lbase[j], 1);
        entries[slot] = make_uint2((rl << 18) | (unsigned)col[k],
                                   __float_as_uint(vals[k]));
    }
}

// P4: one block per bucket. Stage entries in LDS, counting-sort by the 74
// local rows, rewrite the region IN PLACE as fine CSR int2{col,val}; emit
// rowptr for the bucket's rows.
__global__ __launch_bounds__(256) void p4_sort(
    const int* __restrict__ bucketbase, uint2* __restrict__ entries,
    int* __restrict__ rowptr) {
    __shared__ uint2 stage[CAP];
    __shared__ int cnt[128], scanb[128], wp[128];
    int t = threadIdx.x, b = blockIdx.x;
    int base = bucketbase[b];
    int n = bucketbase[b + 1] - base;
    if (n > CAP) n = CAP;   // statistically impossible; avoids LDS overrun
    if (t < 128) cnt[t] = 0;
    __syncthreads();
    for (int i = t; i < n; i += 256) {
        uint2 e = entries[base + i];
        stage[i] = e;
        atomicAdd(&cnt[e.x >> 18], 1);
    }
    __syncthreads();
    if (t < 128) scanb[t] = cnt[t];
    __syncthreads();
    for (int off = 1; off < 128; off <<= 1) {
        int w = 0;
        if (t < 128 && t >= off) w = scanb[t - off];
        __syncthreads();
        if (t < 128) scanb[t] += w;
        __syncthreads();
    }
    if (t < RPB) {
        int excl = scanb[t] - cnt[t];
        wp[t] = excl;
        int rg = b * RPB + t;
        if (rg < N_TOTAL) rowptr[rg] = base + excl;
    }
    __syncthreads();
    for (int i = t; i < n; i += 256) {
        uint2 e = stage[i];
        unsigned rl = e.x >> 18;
        int pos = atomicAdd(&wp[rl], 1);
        ((int2*)entries)[base + pos] =
            make_int2((int)(e.x & 0x3FFFFu), (int)e.y);
    }
}

// 4 rows/wave, 16 lanes/row, bf16 x gathers (8B/lane = 128B/row).
// y(bf16)[r,:] = sum_j val[j]*x[col[j],:];  out(fp32)[r,:] = (out + acc)*scale
__global__ __launch_bounds__(256) void spmm_csr_kernel(
    const int* __restrict__ rowptr, const int2* __restrict__ csr,
    const ushort4* __restrict__ x4, ushort4* __restrict__ y4,
    float4* __restrict__ out, float scale) {
    int gid = blockIdx.x * 256 + threadIdx.x;
    int lane = threadIdx.x & 63;
    int group = lane >> 4;          // 0..3: row within wave
    int chunk = lane & 15;          // 4-dim chunk of the row
    int r = (gid >> 6) * 4 + group;
    if (r >= N_TOTAL) return;
    int start = rowptr[r], end = rowptr[r + 1];
    float4 acc = make_float4(0.f, 0.f, 0.f, 0.f);
    for (int j0 = start; j0 < end; j0 += 16) {
        int j = j0 + chunk;
        int2 pair = make_int2(0, 0);
        if (j < end) pair = csr[j];
        int cnt = min(16, end - j0);
        #pragma unroll 4
        for (int t = 0; t < cnt; t++) {
            int src = group * 16 + t;
            int cc = __shfl(pair.x, src);
            float vv = __int_as_float(__shfl(pair.y, src));
            ushort4 xv = x4[cc * 16 + chunk];
            acc.x += vv * bf2f(xv.x);
            acc.y += vv * bf2f(xv.y);
            acc.z += vv * bf2f(xv.z);
            acc.w += vv * bf2f(xv.w);
        }
    }
    int o = r * 16 + chunk;
    ushort4 yb;
    yb.x = f2bf(acc.x); yb.y = f2bf(acc.y);
    yb.z = f2bf(acc.z); yb.w = f2bf(acc.w);
    y4[o] = yb;
    float4 oo = out[o];
    oo.x = (oo.x + acc.x) * scale;
    oo.y = (oo.y + acc.y) * scale;
    oo.z = (oo.z + acc.z) * scale;
    oo.w = (oo.w + acc.w) * scale;
    out[o] = oo;
}

extern "C" void kernel_launch(void* const* d_in, const int* in_sizes, int n_in,
                              void* d_out, int out_size, void* d_ws, size_t ws_size,
                              hipStream_t stream) {
    const float* user_emb = (const float*)d_in[0];
    const float* item_emb = (const float*)d_in[1];
    const int*   adj_row  = (const int*)d_in[2];
    const int*   adj_col  = (const int*)d_in[3];
    const float* adj_vals = (const float*)d_in[4];
    float* out = (float*)d_out;

    ush*   A          = (ush*)d_ws;                 // 19.2 MB
    ush*   B          = A + NELEM;                  // 19.2 MB
    uint2* entries    = (uint2*)(B + NELEM);        // 38.4 MB (becomes fine CSR)
    int*   histmat    = (int*)(entries + NNZ_C);    // 512*2048 = 4 MB
    int*   basemat    = histmat + NBLK * NB;        // 4 MB
    int*   T          = basemat + NBLK * NB;        // 2048
    int*   bucketbase = T + NB;                     // 2049
    int*   rowptr     = bucketbase + NB + 1;        // 150001

    const int eltBlocks  = (NELEM4 + 255) / 256;
    const int spmmBlocks = N_TOTAL / 16;            // 9375 (exact)

    init_kernel<<<eltBlocks, 256, 0, stream>>>(
        (const float4*)user_emb, (const float4*)item_emb,
        (ushort4*)A, (float4*)out);
    p1_hist<<<NBLK, 256, 0, stream>>>(adj_row, histmat);
    p2a_colscan<<<NB / 256, 256, 0, stream>>>(histmat, basemat, T);
    p2b_scan<<<1, 1024, 0, stream>>>(T, bucketbase, rowptr);
    p3_scatter<<<NBLK, 256, 0, stream>>>(adj_row, adj_col, adj_vals,
                                         basemat, bucketbase, entries);
    p4_sort<<<NB, 256, 0, stream>>>(bucketbase, entries, rowptr);

    spmm_csr_kernel<<<spmmBlocks, 256, 0, stream>>>(rowptr, (const int2*)entries,
        (const ushort4*)A, (ushort4*)B, (float4*)out, 1.0f);
    spmm_csr_kernel<<<spmmBlocks, 256, 0, stream>>>(rowptr, (const int2*)entries,
        (const ushort4*)B, (ushort4*)A, (float4*)out, 1.0f);
    spmm_csr_kernel<<<spmmBlocks, 256, 0, stream>>>(rowptr, (const int2*)entries,
        (const ushort4*)A, (ushort4*)B, (float4*)out, 0.25f);
}

// Round 7
// 616.167 us; speedup vs baseline: 5.3720x; 1.0368x over previous
//
#include <hip/hip_runtime.h>

#define N_USERS 100000
#define N_ITEMS 50000
#define N_TOTAL 150000
#define DIM 64
#define NNZ_C 4800000
#define NELEM (N_TOTAL * DIM)        // 9,600,000 elements
#define NELEM4 (NELEM / 4)           // 2,400,000 x4-vectors

#define RPB 74                       // rows per bucket
#define NB 2048                      // buckets (2048*74 >= 150000)
#define NBLK 512                     // scatter blocks (keeps write segments large)
#define CHUNK (NNZ_C / NBLK)         // 9375 nnz per scatter block (exact)
#define CAP 4096                     // max entries/bucket staged (mean 2344)

typedef unsigned short ush;

__device__ __forceinline__ float bf2f(ush u) {
    return __uint_as_float(((unsigned)u) << 16);
}
__device__ __forceinline__ ush f2bf(float f) {   // round-to-nearest-even
    unsigned u = __float_as_uint(f);
    return (ush)((u + 0x7fffu + ((u >> 16) & 1u)) >> 16);
}

// init: A(bf16) = concat(user,item) = e0; out(fp32) = e0
__global__ __launch_bounds__(256) void init_kernel(
    const float4* __restrict__ user, const float4* __restrict__ item,
    ushort4* __restrict__ A16, float4* __restrict__ out) {
    int i = blockIdx.x * 256 + threadIdx.x;
    if (i >= NELEM4) return;
    const int u4 = N_USERS * DIM / 4;
    float4 v = (i < u4) ? user[i] : item[i - u4];
    ushort4 b;
    b.x = f2bf(v.x); b.y = f2bf(v.y); b.z = f2bf(v.z); b.w = f2bf(v.w);
    A16[i] = b;
    out[i] = v;
}

// P1: per-block bucket histogram in LDS; 1024 threads for full occupancy
// (2 blocks/CU x 16 waves = 32 waves/CU).
__global__ __launch_bounds__(1024) void p1_hist(
    const int* __restrict__ row, int* __restrict__ histmat) {
    __shared__ int h[NB];
    int t = threadIdx.x, b = blockIdx.x;
    for (int j = t; j < NB; j += 1024) h[j] = 0;
    __syncthreads();
    int kbeg = b * CHUNK, kend = kbeg + CHUNK;
    for (int k = kbeg + t; k < kend; k += 1024) {
        unsigned r = (unsigned)row[k];
        atomicAdd(&h[r / RPB], 1);
    }
    __syncthreads();
    for (int j = t; j < NB; j += 1024) histmat[b * NB + j] = h[j];
}

// P2a: column-wise running sum over blocks: basemat[b][j] = sum_{b'<b} hist,
// T[j] = bucket total.
__global__ __launch_bounds__(256) void p2a_colscan(
    const int* __restrict__ histmat, int* __restrict__ basemat,
    int* __restrict__ T) {
    int j = blockIdx.x * 256 + threadIdx.x;   // 0..NB-1
    int run = 0;
    for (int b = 0; b < NBLK; b++) {
        basemat[b * NB + j] = run;
        run += histmat[b * NB + j];
    }
    T[j] = run;
}

// P2b: single block exclusive scan of T[2048] -> bucketbase[0..2048]
__global__ __launch_bounds__(1024) void p2b_scan(
    const int* __restrict__ T, int* __restrict__ bucketbase,
    int* __restrict__ rowptr) {
    __shared__ int s[1024];
    int t = threadIdx.x;
    int v0 = T[2 * t], v1 = T[2 * t + 1];
    int pair = v0 + v1;
    s[t] = pair;
    __syncthreads();
    for (int off = 1; off < 1024; off <<= 1) {
        int w = (t >= off) ? s[t - off] : 0;
        __syncthreads();
        s[t] += w;
        __syncthreads();
    }
    int excl = s[t] - pair;
    bucketbase[2 * t] = excl;
    bucketbase[2 * t + 1] = excl + v0;
    if (t == 1023) { bucketbase[NB] = s[t]; rowptr[N_TOTAL] = NNZ_C; }
}

// P3: deterministic scatter into bucket-grouped entries; zero global atomics.
// 1024 threads/block: 2 blocks/CU x 16 waves = full 32 waves/CU while NBLK
// stays 512 (preserving ~37B per (block,bucket) write segments).
__global__ __launch_bounds__(1024) void p3_scatter(
    const int* __restrict__ row, const int* __restrict__ col,
    const float* __restrict__ vals, const int* __restrict__ basemat,
    const int* __restrict__ bucketbase, uint2* __restrict__ entries) {
    __shared__ int lbase[NB];
    int t = threadIdx.x, b = blockIdx.x;
    for (int j = t; j < NB; j += 1024)
        lbase[j] = bucketbase[j] + basemat[b * NB + j];
    __syncthreads();
    int kbeg = b * CHUNK, kend = kbeg + CHUNK;
    for (int k = kbeg + t; k < kend; k += 1024) {
        unsigned r = (unsigned)row[k];
        unsigned j = r / RPB;
        unsigned rl = r - j * RPB;
        int slot = atomicAdd(&lbase[j], 1);
        entries[slot] = make_uint2((rl << 18) | (unsigned)col[k],
                                   __float_as_uint(vals[k]));
    }
}

// P4: one block per bucket; stage in LDS, counting-sort by 74 local rows,
// rewrite region in place as fine CSR int2{col,val}; emit rowptr.
__global__ __launch_bounds__(512) void p4_sort(
    const int* __restrict__ bucketbase, uint2* __restrict__ entries,
    int* __restrict__ rowptr) {
    __shared__ uint2 stage[CAP];
    __shared__ int cnt[128], scanb[128], wp[128];
    int t = threadIdx.x, b = blockIdx.x;
    int base = bucketbase[b];
    int n = bucketbase[b + 1] - base;
    if (n > CAP) n = CAP;   // statistically impossible; avoids LDS overrun
    if (t < 128) cnt[t] = 0;
    __syncthreads();
    for (int i = t; i < n; i += 512) {
        uint2 e = entries[base + i];
        stage[i] = e;
        atomicAdd(&cnt[e.x >> 18], 1);
    }
    __syncthreads();
    if (t < 128) scanb[t] = cnt[t];
    __syncthreads();
    for (int off = 1; off < 128; off <<= 1) {
        int w = 0;
        if (t < 128 && t >= off) w = scanb[t - off];
        __syncthreads();
        if (t < 128) scanb[t] += w;
        __syncthreads();
    }
    if (t < RPB) {
        int excl = scanb[t] - cnt[t];
        wp[t] = excl;
        int rg = b * RPB + t;
        if (rg < N_TOTAL) rowptr[rg] = base + excl;
    }
    __syncthreads();
    for (int i = t; i < n; i += 512) {
        uint2 e = stage[i];
        unsigned rl = e.x >> 18;
        int pos = atomicAdd(&wp[rl], 1);
        ((int2*)entries)[base + pos] =
            make_int2((int)(e.x & 0x3FFFFu), (int)e.y);
    }
}

// 4 rows/wave, 16 lanes/row, bf16 gathers. y = A_sparse * x (bf16 out).
__global__ __launch_bounds__(256) void spmm_csr_kernel(
    const int* __restrict__ rowptr, const int2* __restrict__ csr,
    const ushort4* __restrict__ x4, ushort4* __restrict__ y4) {
    int gid = blockIdx.x * 256 + threadIdx.x;
    int lane = threadIdx.x & 63;
    int group = lane >> 4;          // 0..3: row within wave
    int chunk = lane & 15;          // 4-dim chunk of the row
    int r = (gid >> 6) * 4 + group;
    if (r >= N_TOTAL) return;
    int start = rowptr[r], end = rowptr[r + 1];
    float4 acc = make_float4(0.f, 0.f, 0.f, 0.f);
    for (int j0 = start; j0 < end; j0 += 16) {
        int j = j0 + chunk;
        int2 pair = make_int2(0, 0);
        if (j < end) pair = csr[j];
        int cnt = min(16, end - j0);
        #pragma unroll 4
        for (int t = 0; t < cnt; t++) {
            int src = group * 16 + t;
            int cc = __shfl(pair.x, src);
            float vv = __int_as_float(__shfl(pair.y, src));
            ushort4 xv = x4[cc * 16 + chunk];
            acc.x += vv * bf2f(xv.x);
            acc.y += vv * bf2f(xv.y);
            acc.z += vv * bf2f(xv.z);
            acc.w += vv * bf2f(xv.w);
        }
    }
    int o = r * 16 + chunk;
    ushort4 yb;
    yb.x = f2bf(acc.x); yb.y = f2bf(acc.y);
    yb.z = f2bf(acc.z); yb.w = f2bf(acc.w);
    y4[o] = yb;
}

// final: out = (out(e0) + B(e1) + C(e2) + A(e3)) * 0.25
__global__ __launch_bounds__(256) void merge_kernel(
    float4* __restrict__ out, const ushort4* __restrict__ e1,
    const ushort4* __restrict__ e2, const ushort4* __restrict__ e3) {
    int i = blockIdx.x * 256 + threadIdx.x;
    if (i >= NELEM4) return;
    float4 o = out[i];
    ushort4 a = e1[i], b = e2[i], c = e3[i];
    o.x = (o.x + bf2f(a.x) + bf2f(b.x) + bf2f(c.x)) * 0.25f;
    o.y = (o.y + bf2f(a.y) + bf2f(b.y) + bf2f(c.y)) * 0.25f;
    o.z = (o.z + bf2f(a.z) + bf2f(b.z) + bf2f(c.z)) * 0.25f;
    o.w = (o.w + bf2f(a.w) + bf2f(b.w) + bf2f(c.w)) * 0.25f;
    out[i] = o;
}

extern "C" void kernel_launch(void* const* d_in, const int* in_sizes, int n_in,
                              void* d_out, int out_size, void* d_ws, size_t ws_size,
                              hipStream_t stream) {
    const float* user_emb = (const float*)d_in[0];
    const float* item_emb = (const float*)d_in[1];
    const int*   adj_row  = (const int*)d_in[2];
    const int*   adj_col  = (const int*)d_in[3];
    const float* adj_vals = (const float*)d_in[4];
    float* out = (float*)d_out;

    ush*   A          = (ush*)d_ws;                 // 19.2 MB (e0, then e3)
    ush*   B          = A + NELEM;                  // 19.2 MB (e1)
    ush*   C          = B + NELEM;                  // 19.2 MB (e2)
    uint2* entries    = (uint2*)(C + NELEM);        // 38.4 MB (becomes fine CSR)
    int*   histmat    = (int*)(entries + NNZ_C);    // 512*2048 = 4 MB
    int*   basemat    = histmat + NBLK * NB;        // 4 MB
    int*   T          = basemat + NBLK * NB;        // 2048
    int*   bucketbase = T + NB;                     // 2049
    int*   rowptr     = bucketbase + NB + 1;        // 150001

    const int eltBlocks  = (NELEM4 + 255) / 256;
    const int spmmBlocks = N_TOTAL / 16;            // 9375 (exact)

    init_kernel<<<eltBlocks, 256, 0, stream>>>(
        (const float4*)user_emb, (const float4*)item_emb,
        (ushort4*)A, (float4*)out);
    p1_hist<<<NBLK, 1024, 0, stream>>>(adj_row, histmat);
    p2a_colscan<<<NB / 256, 256, 0, stream>>>(histmat, basemat, T);
    p2b_scan<<<1, 1024, 0, stream>>>(T, bucketbase, rowptr);
    p3_scatter<<<NBLK, 1024, 0, stream>>>(adj_row, adj_col, adj_vals,
                                          basemat, bucketbase, entries);
    p4_sort<<<NB, 512, 0, stream>>>(bucketbase, entries, rowptr);

    spmm_csr_kernel<<<spmmBlocks, 256, 0, stream>>>(rowptr, (const int2*)entries,
        (const ushort4*)A, (ushort4*)B);    // e1 = S e0
    spmm_csr_kernel<<<spmmBlocks, 256, 0, stream>>>(rowptr, (const int2*)entries,
        (const ushort4*)B, (ushort4*)C);    // e2 = S e1
    spmm_csr_kernel<<<spmmBlocks, 256, 0, stream>>>(rowptr, (const int2*)entries,
        (const ushort4*)C, (ushort4*)A);    // e3 = S e2
    merge_kernel<<<eltBlocks, 256, 0, stream>>>(
        (float4*)out, (const ushort4*)B, (const ushort4*)C, (const ushort4*)A);
}

// Round 8
// 537.474 us; speedup vs baseline: 6.1585x; 1.1464x over previous
//
#include <hip/hip_runtime.h>

#define N_USERS 100000
#define N_ITEMS 50000
#define N_TOTAL 150000
#define DIM 64
#define NNZ_C 4800000
#define NELEM (N_TOTAL * DIM)        // 9,600,000 elements
#define NELEM4 (NELEM / 4)           // 2,400,000 x4-vectors

#define RPB 74                       // rows per bucket
#define NB 2048                      // buckets (2048*74 >= 150000)
#define NBLK 512                     // scatter blocks
#define CHUNK (NNZ_C / NBLK)         // 9375 nnz per scatter block (exact)
#define CAP 4096                     // max entries/bucket staged (mean 2344)

typedef unsigned short ush;

__device__ __forceinline__ float bf2f(ush u) {
    return __uint_as_float(((unsigned)u) << 16);
}
__device__ __forceinline__ ush f2bf(float f) {   // round-to-nearest-even
    unsigned u = __float_as_uint(f);
    return (ush)((u + 0x7fffu + ((u >> 16) & 1u)) >> 16);
}

// init: A(bf16) = concat(user,item) = e0 (out is written only by the fused
// final layer).
__global__ __launch_bounds__(256) void init_kernel(
    const float4* __restrict__ user, const float4* __restrict__ item,
    ushort4* __restrict__ A16) {
    int i = blockIdx.x * 256 + threadIdx.x;
    if (i >= NELEM4) return;
    const int u4 = N_USERS * DIM / 4;
    float4 v = (i < u4) ? user[i] : item[i - u4];
    ushort4 b;
    b.x = f2bf(v.x); b.y = f2bf(v.y); b.z = f2bf(v.z); b.w = f2bf(v.w);
    A16[i] = b;
}

// P1: per-block bucket histogram in LDS -> histmat[block][bucket]
__global__ __launch_bounds__(1024) void p1_hist(
    const int* __restrict__ row, int* __restrict__ histmat) {
    __shared__ int h[NB];
    int t = threadIdx.x, b = blockIdx.x;
    for (int j = t; j < NB; j += 1024) h[j] = 0;
    __syncthreads();
    int kbeg = b * CHUNK, kend = kbeg + CHUNK;
    for (int k = kbeg + t; k < kend; k += 1024) {
        unsigned r = (unsigned)row[k];
        atomicAdd(&h[r / RPB], 1);
    }
    __syncthreads();
    for (int j = t; j < NB; j += 1024) histmat[b * NB + j] = h[j];
}

// P2a: column-wise running sum over blocks: basemat[b][j] = sum_{b'<b} hist,
// T[j] = bucket total.
__global__ __launch_bounds__(256) void p2a_colscan(
    const int* __restrict__ histmat, int* __restrict__ basemat,
    int* __restrict__ T) {
    int j = blockIdx.x * 256 + threadIdx.x;   // 0..NB-1
    int run = 0;
    for (int b = 0; b < NBLK; b++) {
        basemat[b * NB + j] = run;
        run += histmat[b * NB + j];
    }
    T[j] = run;
}

// P2b: single block exclusive scan of T[2048] -> bucketbase[0..2048]
__global__ __launch_bounds__(1024) void p2b_scan(
    const int* __restrict__ T, int* __restrict__ bucketbase,
    int* __restrict__ rowptr) {
    __shared__ int s[1024];
    int t = threadIdx.x;
    int v0 = T[2 * t], v1 = T[2 * t + 1];
    int pair = v0 + v1;
    s[t] = pair;
    __syncthreads();
    for (int off = 1; off < 1024; off <<= 1) {
        int w = (t >= off) ? s[t - off] : 0;
        __syncthreads();
        s[t] += w;
        __syncthreads();
    }
    int excl = s[t] - pair;
    bucketbase[2 * t] = excl;
    bucketbase[2 * t + 1] = excl + v0;
    if (t == 1023) { bucketbase[NB] = s[t]; rowptr[N_TOTAL] = NNZ_C; }
}

// P3: bucket-sort the chunk in LDS, then write runs of consecutive global
// slots (~4.6 entries per (block,bucket) segment) — ~3x fewer write-line
// touches than per-entry scatter. Uses histmat (from P1) instead of
// recounting. LDS ~133KB -> 1 block/CU.
__global__ __launch_bounds__(1024) void p3_scatter(
    const int* __restrict__ row, const int* __restrict__ col,
    const float* __restrict__ vals, const int* __restrict__ histmat,
    const int* __restrict__ basemat, const int* __restrict__ bucketbase,
    uint2* __restrict__ entries) {
    __shared__ int s[1024];
    __shared__ int wp[NB];       // running LDS write position per bucket
    __shared__ int gbase[NB];    // global dest = gbase[j] + local pos
    __shared__ uint2 sorted[CHUNK];
    __shared__ int dest[CHUNK];
    int t = threadIdx.x, b = blockIdx.x;

    // local exclusive scan of this block's 2048 bucket counts (2/thread)
    int c0 = histmat[b * NB + 2 * t];
    int c1 = histmat[b * NB + 2 * t + 1];
    int pair = c0 + c1;
    s[t] = pair;
    __syncthreads();
    for (int off = 1; off < 1024; off <<= 1) {
        int w = (t >= off) ? s[t - off] : 0;
        __syncthreads();
        s[t] += w;
        __syncthreads();
    }
    int excl = s[t] - pair;              // lofs of bucket 2t
    wp[2 * t] = excl;
    wp[2 * t + 1] = excl + c0;
    gbase[2 * t]     = bucketbase[2 * t]     + basemat[b * NB + 2 * t]     - excl;
    gbase[2 * t + 1] = bucketbase[2 * t + 1] + basemat[b * NB + 2 * t + 1] - (excl + c0);
    __syncthreads();

    int kbeg = b * CHUNK, kend = kbeg + CHUNK;
    for (int k = kbeg + t; k < kend; k += 1024) {
        unsigned r = (unsigned)row[k];
        unsigned j = r / RPB;
        unsigned rl = r - j * RPB;
        int pos = atomicAdd(&wp[j], 1);
        sorted[pos] = make_uint2((rl << 18) | (unsigned)col[k],
                                 __float_as_uint(vals[k]));
        dest[pos] = gbase[j] + pos;
    }
    __syncthreads();
    for (int i = t; i < CHUNK; i += 1024)
        entries[dest[i]] = sorted[i];
}

// P4: one block per bucket; stage in LDS, counting-sort by 74 local rows,
// rewrite region in place as fine CSR int2{col,val}; emit rowptr.
__global__ __launch_bounds__(512) void p4_sort(
    const int* __restrict__ bucketbase, uint2* __restrict__ entries,
    int* __restrict__ rowptr) {
    __shared__ uint2 stage[CAP];
    __shared__ int cnt[128], scanb[128], wp[128];
    int t = threadIdx.x, b = blockIdx.x;
    int base = bucketbase[b];
    int n = bucketbase[b + 1] - base;
    if (n > CAP) n = CAP;   // statistically impossible; avoids LDS overrun
    if (t < 128) cnt[t] = 0;
    __syncthreads();
    for (int i = t; i < n; i += 512) {
        uint2 e = entries[base + i];
        stage[i] = e;
        atomicAdd(&cnt[e.x >> 18], 1);
    }
    __syncthreads();
    if (t < 128) scanb[t] = cnt[t];
    __syncthreads();
    for (int off = 1; off < 128; off <<= 1) {
        int w = 0;
        if (t < 128 && t >= off) w = scanb[t - off];
        __syncthreads();
        if (t < 128) scanb[t] += w;
        __syncthreads();
    }
    if (t < RPB) {
        int excl = scanb[t] - cnt[t];
        wp[t] = excl;
        int rg = b * RPB + t;
        if (rg < N_TOTAL) rowptr[rg] = base + excl;
    }
    __syncthreads();
    for (int i = t; i < n; i += 512) {
        uint2 e = stage[i];
        unsigned rl = e.x >> 18;
        int pos = atomicAdd(&wp[rl], 1);
        ((int2*)entries)[base + pos] =
            make_int2((int)(e.x & 0x3FFFFu), (int)e.y);
    }
}

// 4 rows/wave, 16 lanes/row, bf16 gathers. y = S * x (bf16 out).
__global__ __launch_bounds__(256) void spmm_csr_kernel(
    const int* __restrict__ rowptr, const int2* __restrict__ csr,
    const ushort4* __restrict__ x4, ushort4* __restrict__ y4) {
    int gid = blockIdx.x * 256 + threadIdx.x;
    int lane = threadIdx.x & 63;
    int group = lane >> 4;
    int chunk = lane & 15;
    int r = (gid >> 6) * 4 + group;
    if (r >= N_TOTAL) return;
    int start = rowptr[r], end = rowptr[r + 1];
    float4 acc = make_float4(0.f, 0.f, 0.f, 0.f);
    for (int j0 = start; j0 < end; j0 += 16) {
        int j = j0 + chunk;
        int2 pair = make_int2(0, 0);
        if (j < end) pair = csr[j];
        int cnt = min(16, end - j0);
        #pragma unroll 4
        for (int t = 0; t < cnt; t++) {
            int src = group * 16 + t;
            int cc = __shfl(pair.x, src);
            float vv = __int_as_float(__shfl(pair.y, src));
            ushort4 xv = x4[cc * 16 + chunk];
            acc.x += vv * bf2f(xv.x);
            acc.y += vv * bf2f(xv.y);
            acc.z += vv * bf2f(xv.z);
            acc.w += vv * bf2f(xv.w);
        }
    }
    int o = r * 16 + chunk;
    ushort4 yb;
    yb.x = f2bf(acc.x); yb.y = f2bf(acc.y);
    yb.z = f2bf(acc.z); yb.w = f2bf(acc.w);
    y4[o] = yb;
}

// final layer fused with merge: acc = S*e2 (fp32 regs);
// out = (e0 + e1 + e2 + acc) * 0.25
__global__ __launch_bounds__(256) void spmm_merge_kernel(
    const int* __restrict__ rowptr, const int2* __restrict__ csr,
    const ushort4* __restrict__ x4 /*e2*/, const ushort4* __restrict__ e0,
    const ushort4* __restrict__ e1, float4* __restrict__ out) {
    int gid = blockIdx.x * 256 + threadIdx.x;
    int lane = threadIdx.x & 63;
    int group = lane >> 4;
    int chunk = lane & 15;
    int r = (gid >> 6) * 4 + group;
    if (r >= N_TOTAL) return;
    int start = rowptr[r], end = rowptr[r + 1];
    float4 acc = make_float4(0.f, 0.f, 0.f, 0.f);
    for (int j0 = start; j0 < end; j0 += 16) {
        int j = j0 + chunk;
        int2 pair = make_int2(0, 0);
        if (j < end) pair = csr[j];
        int cnt = min(16, end - j0);
        #pragma unroll 4
        for (int t = 0; t < cnt; t++) {
            int src = group * 16 + t;
            int cc = __shfl(pair.x, src);
            float vv = __int_as_float(__shfl(pair.y, src));
            ushort4 xv = x4[cc * 16 + chunk];
            acc.x += vv * bf2f(xv.x);
            acc.y += vv * bf2f(xv.y);
            acc.z += vv * bf2f(xv.z);
            acc.w += vv * bf2f(xv.w);
        }
    }
    int o = r * 16 + chunk;
    ushort4 a = e0[o], b = e1[o], c = x4[o];
    float4 oo;
    oo.x = (bf2f(a.x) + bf2f(b.x) + bf2f(c.x) + acc.x) * 0.25f;
    oo.y = (bf2f(a.y) + bf2f(b.y) + bf2f(c.y) + acc.y) * 0.25f;
    oo.z = (bf2f(a.z) + bf2f(b.z) + bf2f(c.z) + acc.z) * 0.25f;
    oo.w = (bf2f(a.w) + bf2f(b.w) + bf2f(c.w) + acc.w) * 0.25f;
    out[o] = oo;
}

extern "C" void kernel_launch(void* const* d_in, const int* in_sizes, int n_in,
                              void* d_out, int out_size, void* d_ws, size_t ws_size,
                              hipStream_t stream) {
    const float* user_emb = (const float*)d_in[0];
    const float* item_emb = (const float*)d_in[1];
    const int*   adj_row  = (const int*)d_in[2];
    const int*   adj_col  = (const int*)d_in[3];
    const float* adj_vals = (const float*)d_in[4];
    float* out = (float*)d_out;

    ush*   A          = (ush*)d_ws;                 // 19.2 MB (e0)
    ush*   B          = A + NELEM;                  // 19.2 MB (e1)
    ush*   C          = B + NELEM;                  // 19.2 MB (e2)
    uint2* entries    = (uint2*)(C + NELEM);        // 38.4 MB (becomes fine CSR)
    int*   histmat    = (int*)(entries + NNZ_C);    // 512*2048 = 4 MB
    int*   basemat    = histmat + NBLK * NB;        // 4 MB
    int*   T          = basemat + NBLK * NB;        // 2048
    int*   bucketbase = T + NB;                     // 2049
    int*   rowptr     = bucketbase + NB + 1;        // 150001

    const int eltBlocks  = (NELEM4 + 255) / 256;
    const int spmmBlocks = N_TOTAL / 16;            // 9375 (exact)

    init_kernel<<<eltBlocks, 256, 0, stream>>>(
        (const float4*)user_emb, (const float4*)item_emb, (ushort4*)A);
    p1_hist<<<NBLK, 1024, 0, stream>>>(adj_row, histmat);
    p2a_colscan<<<NB / 256, 256, 0, stream>>>(histmat, basemat, T);
    p2b_scan<<<1, 1024, 0, stream>>>(T, bucketbase, rowptr);
    p3_scatter<<<NBLK, 1024, 0, stream>>>(adj_row, adj_col, adj_vals,
                                          histmat, basemat, bucketbase, entries);
    p4_sort<<<NB, 512, 0, stream>>>(bucketbase, entries, rowptr);

    spmm_csr_kernel<<<spmmBlocks, 256, 0, stream>>>(rowptr, (const int2*)entries,
        (const ushort4*)A, (ushort4*)B);    // e1 = S e0
    spmm_csr_kernel<<<spmmBlocks, 256, 0, stream>>>(rowptr, (const int2*)entries,
        (const ushort4*)B, (ushort4*)C);    // e2 = S e1
    spmm_merge_kernel<<<spmmBlocks, 256, 0, stream>>>(rowptr, (const int2*)entries,
        (const ushort4*)C, (const ushort4*)A, (const ushort4*)B, (float4*)out);
}